// Round 10
// baseline (361.640 us; speedup 1.0000x reference)
//
#include <hip/hip_runtime.h>

#define BB 4
#define PP 2048
#define CCLUS 512
#define DD 1024
#define HH 16
#define DHH 64

typedef __attribute__((ext_vector_type(8))) short short8;
typedef __attribute__((ext_vector_type(4))) float floatx4;
typedef unsigned short u16;
typedef unsigned int u32;
typedef unsigned long long u64;

__device__ __forceinline__ float bf2f(u16 u) {
  union { u32 i; float f; } v; v.i = ((u32)u) << 16; return v.f;
}
__device__ __forceinline__ u16 f2bf(float f) {
  union { float f; u32 i; } v; v.f = f;
  u32 x = v.i;
  return (u16)((x + 0x7fffu + ((x >> 16) & 1u)) >> 16);  // RNE
}
__device__ __forceinline__ u64 pack4(float a, float b, float c, float d) {
  return (u64)f2bf(a) | ((u64)f2bf(b) << 16) | ((u64)f2bf(c) << 32) | ((u64)f2bf(d) << 48);
}

__device__ __forceinline__ floatx4 mfma16(short8 a, short8 b, floatx4 c) {
  return __builtin_amdgcn_mfma_f32_16x16x32_bf16(a, b, c, 0, 0, 0);
}

// async global->LDS, 16B/lane; LDS dest = wave-uniform base + lane*16 (m97)
__device__ __forceinline__ void gload_lds16(const u16* g, u16* l) {
  __builtin_amdgcn_global_load_lds(
      (const __attribute__((address_space(1))) u32*)g,
      (__attribute__((address_space(3))) u32*)l, 16, 0, 0);
}

// ---------------- merged prep: cast para/cluster + transpose Wq/Wk/Wv ----------------
// blocks [0,3072): weight-transpose tiles (3 x 32 x 32); blocks [3072,4096):
// grid-stride f32->bf16 cast of para+cluster.
__global__ __launch_bounds__(256) void prep_k(
    const float* __restrict__ para, const float* __restrict__ cluster,
    const float* __restrict__ Wq, const float* __restrict__ Wk, const float* __restrict__ Wv,
    u16* __restrict__ Ap, u16* __restrict__ Ac,
    u16* __restrict__ WqT, u16* __restrict__ WkT, u16* __restrict__ WvT) {
  const int tid = threadIdx.x;
  if (blockIdx.x < 3072) {
    __shared__ u16 tile[32][33];
    const int job = blockIdx.x;
    const int z = job >> 10;             // 0..2
    const int t = job & 1023;
    const int bx = t & 31, by = t >> 5;
    const float* src = (z == 0) ? Wq : (z == 1) ? Wk : Wv;
    u16* dst = (z == 0) ? WqT : (z == 1) ? WkT : WvT;
    const int c = tid & 31, r0 = tid >> 5;     // 8 rows/pass
#pragma unroll
    for (int rr = 0; rr < 4; rr++) {
      const int row = r0 + rr * 8;
      tile[row][c] = f2bf(src[(size_t)(by * 32 + row) * DD + bx * 32 + c]);
    }
    __syncthreads();
#pragma unroll
    for (int rr = 0; rr < 4; rr++) {
      const int row = r0 + rr * 8;
      dst[(size_t)(bx * 32 + row) * DD + by * 32 + c] = tile[c][row];
    }
  } else {
    const int NP4 = (BB * PP * DD) / 4;
    const int NC4 = (BB * CCLUS * DD) / 4;
    const int stride = 1024 * 256;
    for (int i = (blockIdx.x - 3072) * 256 + tid; i < NP4 + NC4; i += stride) {
      const float* src; u16* dst; int j;
      if (i < NP4) { src = para; dst = Ap; j = i; }
      else         { src = cluster; dst = Ac; j = i - NP4; }
      const float4 v = *(const float4*)(src + (size_t)j * 4);
      *(u64*)(dst + (size_t)j * 4) = pack4(v.x, v.y, v.z, v.w);
    }
  }
}

// ---------------- fused QKV GEMM v5: BK=32 (round-2 proven) + fused V-transpose ----------------
// Q -> Qb[b*P+p][1024], scale folds 1/sqrt(DH) AND log2(e) (attn uses 2^x)
// K -> Kp[b][h][c][64]   (per-head row-major)
// V -> Vt[(b*16+h)*64+d][512]  DIRECTLY (LDS-transposed epilogue; no Vb pass)
// packed grid.x=96: [0,64)=Q, [64,80)=K, [80,96)=V.
__global__ __launch_bounds__(256) void qkv_gemm5(
    const u16* __restrict__ Ap, const u16* __restrict__ Ac,
    const u16* __restrict__ WqT, const u16* __restrict__ WkT, const u16* __restrict__ WvT,
    const float* __restrict__ bq, const float* __restrict__ bk, const float* __restrict__ bv,
    u16* __restrict__ Qb, u16* __restrict__ Kp, u16* __restrict__ Vt) {
  const int bx = blockIdx.x;
  const u16* A; const u16* BT; const float* bias; float scale; int mt, mode;
  if (bx < 64)      { A = Ap; BT = WqT; bias = bq; scale = 0.18033688f; mt = bx;      mode = 0; }
  else if (bx < 80) { A = Ac; BT = WkT; bias = bk; scale = 1.0f;        mt = bx - 64; mode = 1; }
  else              { A = Ac; BT = WvT; bias = bv; scale = 1.0f;        mt = bx - 80; mode = 2; }

  // 32KB shared: As/Bs for the K-loop; T2 (V-transpose) overlays them after.
  __shared__ __align__(16) u16 SH[16384];
  u16* As = SH;
  u16* Bs = SH + 4096;
  u16* T2 = SH;   // [64 cols(d)][128 rows(c)], row XOR-swizzled by (col&7)<<3

  const int tid = threadIdx.x;
  const int w = tid >> 6, lane = tid & 63, quad = lane >> 4, cidx = lane & 15;
  const int wy = w >> 1, wx = w & 1;
  const int m0 = mt * 128, n0 = blockIdx.y * 128;

  floatx4 acc[4][4];
#pragma unroll
  for (int i = 0; i < 4; i++)
#pragma unroll
    for (int j = 0; j < 4; j++) acc[i][j] = (floatx4){0.f, 0.f, 0.f, 0.f};

  const int row0 = tid >> 2, kc0 = tid & 3;
  const int offG0 = row0 * 1024 + kc0 * 8;
  const int offG1 = (row0 + 64) * 1024 + kc0 * 8;
  u16* ldsA0 = As + (size_t)(w * 64) * 8;
  u16* ldsA1 = As + (size_t)(w * 64 + 256) * 8;
  u16* ldsB0 = Bs + (size_t)(w * 64) * 8;
  u16* ldsB1 = Bs + (size_t)(w * 64 + 256) * 8;

  const u16* Abase = A + (size_t)m0 * 1024;
  const u16* Bbase = BT + (size_t)n0 * 1024;

  for (int kt = 0; kt < 32; kt++) {
    const u16* Ak = Abase + kt * 32;
    const u16* Bk = Bbase + kt * 32;
    gload_lds16(Ak + offG0, ldsA0);
    gload_lds16(Ak + offG1, ldsA1);
    gload_lds16(Bk + offG0, ldsB0);
    gload_lds16(Bk + offG1, ldsB1);
    __syncthreads();

    short8 af[4], bfr[4];
#pragma unroll
    for (int i = 0; i < 4; i++) {
      int ra = wy * 64 + i * 16 + cidx;
      af[i] = *(const short8*)&As[ra * 32 + quad * 8];
      int rb = wx * 64 + i * 16 + cidx;
      bfr[i] = *(const short8*)&Bs[rb * 32 + quad * 8];
    }
#pragma unroll
    for (int mi = 0; mi < 4; mi++)
#pragma unroll
      for (int ni = 0; ni < 4; ni++)
        acc[mi][ni] = mfma16(af[mi], bfr[ni], acc[mi][ni]);
    __syncthreads();
  }

  if (mode != 2) {
#pragma unroll
    for (int ni = 0; ni < 4; ni++) {
      const int ncol = n0 + wx * 64 + ni * 16 + cidx;
      const float bvv = bias[ncol];
#pragma unroll
      for (int mi = 0; mi < 4; mi++) {
        const int mrow = m0 + wy * 64 + mi * 16 + quad * 4;
        if (mode == 1) {
          const int hh2 = ncol >> 6, dh = ncol & 63;
#pragma unroll
          for (int r = 0; r < 4; r++) {
            const int row = mrow + r;
            const int bb = row >> 9, c = row & 511;
            Kp[((size_t)(bb * HH + hh2) * CCLUS + c) * DHH + dh] = f2bf(acc[mi][ni][r] + bvv);
          }
        } else {
#pragma unroll
          for (int r = 0; r < 4; r++) {
            float v = (acc[mi][ni][r] + bvv) * scale;
            Qb[(size_t)(mrow + r) * 1024 + ncol] = f2bf(v);
          }
        }
      }
    }
  } else {
    // V: transpose 128(c) x 128(d=2 heads) tile via LDS, store Vt rows directly.
    const int b = m0 >> 9;          // rows m0..m0+127 stay within one b (128|512)
    const int c0g = m0 & 511;
    const int h0g = n0 >> 6;        // global head of col-block 0
#pragma unroll
    for (int p = 0; p < 2; p++) {
      if (wx == p) {
#pragma unroll
        for (int ni = 0; ni < 4; ni++) {
          const int col = ni * 16 + cidx;                  // d-local 0..63
          const float bvv = bias[n0 + wx * 64 + col];
          const int swzv = (col & 7) << 3;
#pragma unroll
          for (int mi = 0; mi < 4; mi++) {
            const int rowb = wy * 64 + mi * 16 + quad * 4; // c-local, %4==0
            *(u64*)&T2[col * 128 + (rowb ^ swzv)] =
                pack4(acc[mi][ni][0] + bvv, acc[mi][ni][1] + bvv,
                      acc[mi][ni][2] + bvv, acc[mi][ni][3] + bvv);
          }
        }
      }
      __syncthreads();
      {
        const int col = tid >> 2, quarter = tid & 3;
        const int swzv = (col & 7) << 3;
        u16* vrow = Vt + ((size_t)(b * HH + h0g + p) * 64 + col) * 512 + c0g + quarter * 32;
#pragma unroll
        for (int j = 0; j < 4; j++) {
          const short8 vv = *(const short8*)&T2[col * 128 + ((quarter * 32 + j * 8) ^ swzv)];
          *(short8*)(vrow + j * 8) = vv;
        }
      }
      __syncthreads();   // T2 free before pass 1 overwrites
    }
  }
}

// ---------------- fused masked attention v10: NO LDS, NO BARRIERS ----------------
// K/V per (b,h) are 64KB each, L2-resident across the 16 p-blocks that share
// them (Common-mistake #7 / m169: staging L2-fit data is pure overhead).
// All fragments gathered directly from global/L2; each gather instruction is
// a dense 16-line read (K: 16x64 contiguous subtile; V: 16 rows x 32 u16).
// Waves are fully independent -> zero __syncthreads, zero barrier convoys,
// zero race surface. Math/fragment layouts/summation order identical to v5.
__global__ __launch_bounds__(512, 4) void attn_k10(
    const u16* __restrict__ Qb, const u16* __restrict__ Kp, const u16* __restrict__ Vt,
    const float* __restrict__ edge, float* __restrict__ ctx) {
  const int b = blockIdx.z, h = blockIdx.y, p0 = blockIdx.x * 128;
  const int tid = threadIdx.x;
  const int w = tid >> 6, lane = tid & 63, quad = lane >> 4, cidx = lane & 15;

  const u16* __restrict__ Kbh = Kp + (size_t)(b * HH + h) * CCLUS * DHH;   // [c][64]
  const u16* __restrict__ Vbh = Vt + (size_t)(b * HH + h) * DHH * CCLUS;   // [d][512]

  // Q frags (B-operand: n=cidx -> p row, k=quad*8+j), loaded once
  const int prow = p0 + w * 16 + cidx;
  const u16* qg = Qb + (size_t)(b * PP + prow) * DD + h * DHH + quad * 8;
  const short8 qf0 = *(const short8*)qg;
  const short8 qf1 = *(const short8*)(qg + 32);
  const float* Erow = edge + (size_t)(b * PP + prow) * CCLUS;

  // per-lane fragment base pointers
  // K A-frag for tile ct: row c = ct*16+cidx, d-chunk quad*8  -> kfp + ct*1024 (+32)
  const u16* kfp = Kbh + (size_t)cidx * DHH + quad * 8;
  // V B-frag for nt, c-group g: row d = nt*16+cidx, c = g*32+quad*8 -> vfp + nt*8192 + g*32
  const u16* vfp = Vbh + (size_t)cidx * CCLUS + quad * 8;

  float srow = 0.f;
  floatx4 oacc[4];
#pragma unroll
  for (int nt = 0; nt < 4; nt++) oacc[nt] = (floatx4){0.f, 0.f, 0.f, 0.f};

#pragma unroll 2
  for (int g = 0; g < 16; g++) {     // 16 groups of 32 c (2 tiles of 16)
    u32 pa[2], pb[2];
#pragma unroll
    for (int tt = 0; tt < 2; tt++) {
      const int ct = g * 2 + tt;
      const short8 kf0 = *(const short8*)(kfp + ct * 1024);
      const short8 kf1 = *(const short8*)(kfp + ct * 1024 + 32);
      floatx4 s4 = (floatx4){0.f, 0.f, 0.f, 0.f};
      __builtin_amdgcn_s_setprio(1);
      s4 = mfma16(kf0, qf0, s4);
      s4 = mfma16(kf1, qf1, s4);
      __builtin_amdgcn_s_setprio(0);
      // lane owns S^T[c = ct*16+quad*4+r][p = prow]
      const float4 e4 = *(const float4*)(Erow + ct * 16 + quad * 4);
      float E[4];
#pragma unroll
      for (int r = 0; r < 4; r++) {
        const float e = (&e4.x)[r];
        float x = fminf(s4[r], 21.6f);       // 2^21.6 ~ e^15 cap
        float ex;
        asm("v_exp_f32 %0, %1\n\ts_nop 0" : "=v"(ex) : "v"(x));  // 2^x
        ex = (e > 0.f) ? ex : 0.f;
        srow += ex;
        E[r] = ex * e;
      }
      asm("v_cvt_pk_bf16_f32 %0, %1, %2" : "=v"(pa[tt]) : "v"(E[0]), "v"(E[1]));
      asm("v_cvt_pk_bf16_f32 %0, %1, %2" : "=v"(pb[tt]) : "v"(E[2]), "v"(E[3]));
    }
    // quad exchange: pl32 then pl16 realizes the PV A-layout exactly.
    asm("v_permlane32_swap_b32 %0, %1" : "+v"(pa[0]), "+v"(pa[1]));
    asm("v_permlane16_swap_b32 %0, %1" : "+v"(pa[0]), "+v"(pa[1]));
    asm("v_permlane32_swap_b32 %0, %1" : "+v"(pb[0]), "+v"(pb[1]));
    asm("v_permlane16_swap_b32 %0, %1" : "+v"(pb[0]), "+v"(pb[1]));
    union { u32 u[4]; short8 s; } af;
    af.u[0] = pa[0]; af.u[1] = pb[0]; af.u[2] = pa[1]; af.u[3] = pb[1];
    // PV: A = P[p=cidx][c=g*32+8q+j], B = V^T gathered from L2
    __builtin_amdgcn_s_setprio(1);
#pragma unroll
    for (int nt = 0; nt < 4; nt++) {
      const short8 vb = *(const short8*)(vfp + nt * 8192 + g * 32);
      oacc[nt] = mfma16(af.s, vb, oacc[nt]);
    }
    __builtin_amdgcn_s_setprio(0);
  }

  // reduce srow across quads (lane^16, lane^32 hold same p, disjoint c)
  srow += __shfl_xor(srow, 16, 64);
  srow += __shfl_xor(srow, 32, 64);
  const float sinv = (srow > 0.f) ? 1.0f / srow : 0.f;

#pragma unroll
  for (int r = 0; r < 4; r++) {
    const float sv = __shfl(sinv, quad * 4 + r, 16);  // sinv of p-local quad*4+r
#pragma unroll
    for (int nt = 0; nt < 4; nt++) {
      const size_t off =
          (size_t)(b * PP + p0 + w * 16 + quad * 4 + r) * DD + h * DHH + nt * 16 + cidx;
      ctx[off] = oacc[nt][r] * sv;
    }
  }
}

// ---------------- LayerNorm over D=1024 (f32 in-place on d_out) ----------------
__global__ __launch_bounds__(256) void ln_k(
    float* buf, const float* __restrict__ gamma, const float* __restrict__ beta) {
  const int row = blockIdx.x, tid = threadIdx.x;
  const int w = tid >> 6, lane = tid & 63;
  float* x = buf + (size_t)row * DD + tid * 4;
  float4 v = *(const float4*)x;
  float s = v.x + v.y + v.z + v.w;
  float sq = v.x * v.x + v.y * v.y + v.z * v.z + v.w * v.w;
#pragma unroll
  for (int off = 1; off < 64; off <<= 1) {
    s += __shfl_xor(s, off, 64);
    sq += __shfl_xor(sq, off, 64);
  }
  __shared__ float red[8];
  if (lane == 0) { red[w] = s; red[4 + w] = sq; }
  __syncthreads();
  s = red[0] + red[1] + red[2] + red[3];
  sq = red[4] + red[5] + red[6] + red[7];
  const float mu = s * (1.f / 1024.f);
  const float var = sq * (1.f / 1024.f) - mu * mu;
  const float rs = rsqrtf(fmaxf(var, 0.f) + 1e-6f);
  const float4 gr = *(const float4*)(gamma + tid * 4);
  const float4 br = *(const float4*)(beta + tid * 4);
  float4 y;
  y.x = (v.x - mu) * rs * gr.x + br.x;
  y.y = (v.y - mu) * rs * gr.y + br.y;
  y.z = (v.z - mu) * rs * gr.z + br.z;
  y.w = (v.w - mu) * rs * gr.w + br.w;
  *(float4*)x = y;
}

extern "C" void kernel_launch(void* const* d_in, const int* in_sizes, int n_in,
                              void* d_out, int out_size, void* d_ws, size_t ws_size,
                              hipStream_t stream) {
  const float* para    = (const float*)d_in[0];
  const float* cluster = (const float*)d_in[1];
  const float* edge    = (const float*)d_in[2];
  const float* Wq      = (const float*)d_in[3];
  const float* bq      = (const float*)d_in[4];
  const float* Wk      = (const float*)d_in[5];
  const float* bk      = (const float*)d_in[6];
  const float* Wv      = (const float*)d_in[7];
  const float* bv      = (const float*)d_in[8];
  const float* gamma   = (const float*)d_in[9];
  const float* beta    = (const float*)d_in[10];
  float* out = (float*)d_out;   // ctx lives here (attn writes f32, LN in-place)

  // bf16 workspace: 25M u16 = 50 MB
  u16* WqT = (u16*)d_ws;                        // 1M
  u16* WkT = WqT + (size_t)1024 * 1024;         // 1M
  u16* WvT = WkT + (size_t)1024 * 1024;         // 1M
  u16* Qb  = WvT + (size_t)1024 * 1024;         // 8M
  u16* Kp  = Qb  + (size_t)8192 * 1024;         // 2M  [b][h][c][64]
  u16* Vt  = Kp  + (size_t)2048 * 1024;         // 2M  [b][h][d][512]
  u16* Ap  = Vt  + (size_t)2048 * 1024;         // 8M (para bf16)
  u16* Ac  = Ap  + (size_t)8192 * 1024;         // 2M (cluster bf16)

  prep_k<<<dim3(4096), dim3(256), 0, stream>>>(para, cluster, Wq, Wk, Wv,
                                               Ap, Ac, WqT, WkT, WvT);
  qkv_gemm5<<<dim3(96, 8), dim3(256), 0, stream>>>(Ap, Ac, WqT, WkT, WvT,
                                                   bq, bk, bv, Qb, Kp, Vt);
  attn_k10<<<dim3(PP / 128, HH, BB), dim3(512), 0, stream>>>(Qb, Kp, Vt, edge, out);
  ln_k<<<dim3(BB * PP), dim3(256), 0, stream>>>(out, gamma, beta);
}

// Round 11
// 228.322 us; speedup vs baseline: 1.5839x; 1.5839x over previous
//
#include <hip/hip_runtime.h>

#define BB 4
#define PP 2048
#define CCLUS 512
#define DD 1024
#define HH 16
#define DHH 64

typedef __attribute__((ext_vector_type(8))) short short8;
typedef __attribute__((ext_vector_type(4))) float floatx4;
typedef unsigned short u16;
typedef unsigned int u32;
typedef unsigned long long u64;

__device__ __forceinline__ float bf2f(u16 u) {
  union { u32 i; float f; } v; v.i = ((u32)u) << 16; return v.f;
}
__device__ __forceinline__ u16 f2bf(float f) {
  union { float f; u32 i; } v; v.f = f;
  u32 x = v.i;
  return (u16)((x + 0x7fffu + ((x >> 16) & 1u)) >> 16);  // RNE
}
__device__ __forceinline__ u64 pack4(float a, float b, float c, float d) {
  return (u64)f2bf(a) | ((u64)f2bf(b) << 16) | ((u64)f2bf(c) << 32) | ((u64)f2bf(d) << 48);
}

__device__ __forceinline__ floatx4 mfma16(short8 a, short8 b, floatx4 c) {
  return __builtin_amdgcn_mfma_f32_16x16x32_bf16(a, b, c, 0, 0, 0);
}

// async global->LDS, 16B/lane; LDS dest = wave-uniform base + lane*16 (m97)
__device__ __forceinline__ void gload_lds16(const u16* g, u16* l) {
  __builtin_amdgcn_global_load_lds(
      (const __attribute__((address_space(1))) u32*)g,
      (__attribute__((address_space(3))) u32*)l, 16, 0, 0);
}

// ---------------- merged prep: cast para/cluster + transpose Wq/Wk/Wv ----------------
// blocks [0,3072): weight-transpose tiles (3 x 32 x 32); blocks [3072,4096):
// grid-stride f32->bf16 cast of para+cluster.
__global__ __launch_bounds__(256) void prep_k(
    const float* __restrict__ para, const float* __restrict__ cluster,
    const float* __restrict__ Wq, const float* __restrict__ Wk, const float* __restrict__ Wv,
    u16* __restrict__ Ap, u16* __restrict__ Ac,
    u16* __restrict__ WqT, u16* __restrict__ WkT, u16* __restrict__ WvT) {
  const int tid = threadIdx.x;
  if (blockIdx.x < 3072) {
    __shared__ u16 tile[32][33];
    const int job = blockIdx.x;
    const int z = job >> 10;             // 0..2
    const int t = job & 1023;
    const int bx = t & 31, by = t >> 5;
    const float* src = (z == 0) ? Wq : (z == 1) ? Wk : Wv;
    u16* dst = (z == 0) ? WqT : (z == 1) ? WkT : WvT;
    const int c = tid & 31, r0 = tid >> 5;     // 8 rows/pass
#pragma unroll
    for (int rr = 0; rr < 4; rr++) {
      const int row = r0 + rr * 8;
      tile[row][c] = f2bf(src[(size_t)(by * 32 + row) * DD + bx * 32 + c]);
    }
    __syncthreads();
#pragma unroll
    for (int rr = 0; rr < 4; rr++) {
      const int row = r0 + rr * 8;
      dst[(size_t)(bx * 32 + row) * DD + by * 32 + c] = tile[c][row];
    }
  } else {
    const int NP4 = (BB * PP * DD) / 4;
    const int NC4 = (BB * CCLUS * DD) / 4;
    const int stride = 1024 * 256;
    for (int i = (blockIdx.x - 3072) * 256 + tid; i < NP4 + NC4; i += stride) {
      const float* src; u16* dst; int j;
      if (i < NP4) { src = para; dst = Ap; j = i; }
      else         { src = cluster; dst = Ac; j = i - NP4; }
      const float4 v = *(const float4*)(src + (size_t)j * 4);
      *(u64*)(dst + (size_t)j * 4) = pack4(v.x, v.y, v.z, v.w);
    }
  }
}

// ---------------- fused QKV GEMM v5: BK=32 (round-2 proven) + fused V-transpose ----------------
// Q -> Qb[b*P+p][1024], scale folds 1/sqrt(DH) AND log2(e) (attn uses 2^x)
// K -> Kp[b][h][c][64]   (per-head row-major)
// V -> Vt[(b*16+h)*64+d][512]  DIRECTLY (LDS-transposed epilogue; no Vb pass)
// packed grid.x=96: [0,64)=Q, [64,80)=K, [80,96)=V.
__global__ __launch_bounds__(256) void qkv_gemm5(
    const u16* __restrict__ Ap, const u16* __restrict__ Ac,
    const u16* __restrict__ WqT, const u16* __restrict__ WkT, const u16* __restrict__ WvT,
    const float* __restrict__ bq, const float* __restrict__ bk, const float* __restrict__ bv,
    u16* __restrict__ Qb, u16* __restrict__ Kp, u16* __restrict__ Vt) {
  const int bx = blockIdx.x;
  const u16* A; const u16* BT; const float* bias; float scale; int mt, mode;
  if (bx < 64)      { A = Ap; BT = WqT; bias = bq; scale = 0.18033688f; mt = bx;      mode = 0; }
  else if (bx < 80) { A = Ac; BT = WkT; bias = bk; scale = 1.0f;        mt = bx - 64; mode = 1; }
  else              { A = Ac; BT = WvT; bias = bv; scale = 1.0f;        mt = bx - 80; mode = 2; }

  // 32KB shared: As/Bs for the K-loop; T2 (V-transpose) overlays them after.
  __shared__ __align__(16) u16 SH[16384];
  u16* As = SH;
  u16* Bs = SH + 4096;
  u16* T2 = SH;   // [64 cols(d)][128 rows(c)], row XOR-swizzled by (col&7)<<3

  const int tid = threadIdx.x;
  const int w = tid >> 6, lane = tid & 63, quad = lane >> 4, cidx = lane & 15;
  const int wy = w >> 1, wx = w & 1;
  const int m0 = mt * 128, n0 = blockIdx.y * 128;

  floatx4 acc[4][4];
#pragma unroll
  for (int i = 0; i < 4; i++)
#pragma unroll
    for (int j = 0; j < 4; j++) acc[i][j] = (floatx4){0.f, 0.f, 0.f, 0.f};

  const int row0 = tid >> 2, kc0 = tid & 3;
  const int offG0 = row0 * 1024 + kc0 * 8;
  const int offG1 = (row0 + 64) * 1024 + kc0 * 8;
  u16* ldsA0 = As + (size_t)(w * 64) * 8;
  u16* ldsA1 = As + (size_t)(w * 64 + 256) * 8;
  u16* ldsB0 = Bs + (size_t)(w * 64) * 8;
  u16* ldsB1 = Bs + (size_t)(w * 64 + 256) * 8;

  const u16* Abase = A + (size_t)m0 * 1024;
  const u16* Bbase = BT + (size_t)n0 * 1024;

  for (int kt = 0; kt < 32; kt++) {
    const u16* Ak = Abase + kt * 32;
    const u16* Bk = Bbase + kt * 32;
    gload_lds16(Ak + offG0, ldsA0);
    gload_lds16(Ak + offG1, ldsA1);
    gload_lds16(Bk + offG0, ldsB0);
    gload_lds16(Bk + offG1, ldsB1);
    __syncthreads();

    short8 af[4], bfr[4];
#pragma unroll
    for (int i = 0; i < 4; i++) {
      int ra = wy * 64 + i * 16 + cidx;
      af[i] = *(const short8*)&As[ra * 32 + quad * 8];
      int rb = wx * 64 + i * 16 + cidx;
      bfr[i] = *(const short8*)&Bs[rb * 32 + quad * 8];
    }
#pragma unroll
    for (int mi = 0; mi < 4; mi++)
#pragma unroll
      for (int ni = 0; ni < 4; ni++)
        acc[mi][ni] = mfma16(af[mi], bfr[ni], acc[mi][ni]);
    __syncthreads();
  }

  if (mode != 2) {
#pragma unroll
    for (int ni = 0; ni < 4; ni++) {
      const int ncol = n0 + wx * 64 + ni * 16 + cidx;
      const float bvv = bias[ncol];
#pragma unroll
      for (int mi = 0; mi < 4; mi++) {
        const int mrow = m0 + wy * 64 + mi * 16 + quad * 4;
        if (mode == 1) {
          const int hh2 = ncol >> 6, dh = ncol & 63;
#pragma unroll
          for (int r = 0; r < 4; r++) {
            const int row = mrow + r;
            const int bb = row >> 9, c = row & 511;
            Kp[((size_t)(bb * HH + hh2) * CCLUS + c) * DHH + dh] = f2bf(acc[mi][ni][r] + bvv);
          }
        } else {
#pragma unroll
          for (int r = 0; r < 4; r++) {
            float v = (acc[mi][ni][r] + bvv) * scale;
            Qb[(size_t)(mrow + r) * 1024 + ncol] = f2bf(v);
          }
        }
      }
    }
  } else {
    // V: transpose 128(c) x 128(d=2 heads) tile via LDS, store Vt rows directly.
    const int b = m0 >> 9;          // rows m0..m0+127 stay within one b (128|512)
    const int c0g = m0 & 511;
    const int h0g = n0 >> 6;        // global head of col-block 0
#pragma unroll
    for (int p = 0; p < 2; p++) {
      if (wx == p) {
#pragma unroll
        for (int ni = 0; ni < 4; ni++) {
          const int col = ni * 16 + cidx;                  // d-local 0..63
          const float bvv = bias[n0 + wx * 64 + col];
          const int swzv = (col & 7) << 3;
#pragma unroll
          for (int mi = 0; mi < 4; mi++) {
            const int rowb = wy * 64 + mi * 16 + quad * 4; // c-local, %4==0
            *(u64*)&T2[col * 128 + (rowb ^ swzv)] =
                pack4(acc[mi][ni][0] + bvv, acc[mi][ni][1] + bvv,
                      acc[mi][ni][2] + bvv, acc[mi][ni][3] + bvv);
          }
        }
      }
      __syncthreads();
      {
        const int col = tid >> 2, quarter = tid & 3;
        const int swzv = (col & 7) << 3;
        u16* vrow = Vt + ((size_t)(b * HH + h0g + p) * 64 + col) * 512 + c0g + quarter * 32;
#pragma unroll
        for (int j = 0; j < 4; j++) {
          const short8 vv = *(const short8*)&T2[col * 128 + ((quarter * 32 + j * 8) ^ swzv)];
          *(short8*)(vrow + j * 8) = vv;
        }
      }
      __syncthreads();   // T2 free before pass 1 overwrites
    }
  }
}

// ---------------- fused masked attention v5 (proven) + bf16 ctx out ----------------
// 8 waves x 512 threads; block = 128 p-rows, wave = 16 p-rows.
// K[64c][64d], V^T[64d][64c] double-buffered, XOR-swizzled LDS (T2+T3-min).
// S^T = K.Q^T per 16-c tile; lane owns S^T[c=16t+4q+r][p=cidx]. P->bf16 via
// v_cvt_pk_bf16_f32; quad exchange to PV A-layout via permlane32/16_swap (T12).
// No attnS LDS -> 32KB total -> 4 blocks/CU (32 waves, occupancy cap).
// Q was pre-scaled by log2(e)/8 so exp is a single v_exp_f32 (2^x).
// Epilogue writes BF16 ctx (halves write traffic; ln re-reads bf16).
__global__ __launch_bounds__(512, 8) void attn_k5(
    const u16* __restrict__ Qb, const u16* __restrict__ Kp, const u16* __restrict__ Vt,
    const float* __restrict__ edge, u16* __restrict__ ctxb) {
  const int b = blockIdx.z, h = blockIdx.y, p0 = blockIdx.x * 128;
  const int tid = threadIdx.x;
  const int w = tid >> 6, lane = tid & 63, quad = lane >> 4, cidx = lane & 15;

  __shared__ __align__(16) u16 Ks[2][64 * 64];      // [c][d] swizzled, 8KB each
  __shared__ __align__(16) u16 Vs[2][64 * 64];      // [d][c] swizzled, 8KB each

  const u16* __restrict__ Kbh = Kp + (size_t)(b * HH + h) * CCLUS * DHH;
  const u16* __restrict__ Vbh = Vt + (size_t)(b * HH + h) * DHH * CCLUS;

  // Q frags (B-operand: n=cidx -> p row, k=quad*8+j), loaded once
  const int prow = p0 + w * 16 + cidx;
  const u16* qg = Qb + (size_t)(b * PP + prow) * DD + h * DHH + quad * 8;
  const short8 qf0 = *(const short8*)qg;
  const short8 qf1 = *(const short8*)(qg + 32);
  const float* Erow = edge + (size_t)(b * PP + prow) * CCLUS;

  float srow = 0.f;
  floatx4 oacc[4];
#pragma unroll
  for (int nt = 0; nt < 4; nt++) oacc[nt] = (floatx4){0.f, 0.f, 0.f, 0.f};

  // staging geometry: slot=tid (512 slots x 16B = one 8KB buffer)
  const int srow_i = tid >> 3;                        // row 0..63
  const int sc = ((tid & 7) ^ (srow_i & 7)) << 3;     // inverse-swizzled src col (u16)
  const int ldsoff = w * 512;                         // wave window (u16)

  auto STAGE = [&](int cc, int bufi) {
    const u16* kg = Kbh + (size_t)cc * 64 * DHH;
    const u16* vg = Vbh + cc * 64;
    gload_lds16(kg + (size_t)srow_i * DHH + sc, &Ks[bufi][ldsoff]);
    gload_lds16(vg + (size_t)srow_i * CCLUS + sc, &Vs[bufi][ldsoff]);
  };

  STAGE(0, 0);
  __syncthreads();

  const int swz = (cidx & 7) << 3;  // read-side XOR (u16 units), row&7 == cidx&7

  for (int cc = 0; cc < 8; cc++) {
    const int bufi = cc & 1;
    if (cc < 7) STAGE(cc + 1, bufi ^ 1);  // async prefetch into other buffer
    const u16* __restrict__ KsB = &Ks[bufi][0];
    const u16* __restrict__ VsB = &Vs[bufi][0];

#pragma unroll
    for (int ks = 0; ks < 2; ks++) {
      u32 pa[2], pb[2];
#pragma unroll
      for (int tt = 0; tt < 2; tt++) {
        const int t = ks * 2 + tt;
        const int krow = (t * 16 + cidx) * 64;
        const short8 kf0 = *(const short8*)&KsB[krow + ((quad * 8) ^ swz)];
        const short8 kf1 = *(const short8*)&KsB[krow + ((32 + quad * 8) ^ swz)];
        floatx4 s4 = (floatx4){0.f, 0.f, 0.f, 0.f};
        __builtin_amdgcn_s_setprio(1);
        s4 = mfma16(kf0, qf0, s4);
        s4 = mfma16(kf1, qf1, s4);
        __builtin_amdgcn_s_setprio(0);
        // lane owns S^T[c = cc*64+t*16+quad*4+r][p = prow]
        const int ce = cc * 64 + t * 16 + quad * 4;
        const float4 e4 = *(const float4*)(Erow + ce);
        float E[4];
#pragma unroll
        for (int r = 0; r < 4; r++) {
          const float e = (&e4.x)[r];
          float x = fminf(s4[r], 21.6f);       // 2^21.6 ~ e^15 cap
          float ex;
          asm("v_exp_f32 %0, %1\n\ts_nop 0" : "=v"(ex) : "v"(x));  // 2^x, +trans hazard pad
          ex = (e > 0.f) ? ex : 0.f;
          srow += ex;
          E[r] = ex * e;
        }
        asm("v_cvt_pk_bf16_f32 %0, %1, %2" : "=v"(pa[tt]) : "v"(E[0]), "v"(E[1]));
        asm("v_cvt_pk_bf16_f32 %0, %1, %2" : "=v"(pb[tt]) : "v"(E[2]), "v"(E[3]));
      }
      // quad exchange: pl32 then pl16 realizes the PV A-layout exactly.
      asm("v_permlane32_swap_b32 %0, %1" : "+v"(pa[0]), "+v"(pa[1]));
      asm("v_permlane16_swap_b32 %0, %1" : "+v"(pa[0]), "+v"(pa[1]));
      asm("v_permlane32_swap_b32 %0, %1" : "+v"(pb[0]), "+v"(pb[1]));
      asm("v_permlane16_swap_b32 %0, %1" : "+v"(pb[0]), "+v"(pb[1]));
      union { u32 u[4]; short8 s; } af;
      af.u[0] = pa[0]; af.u[1] = pb[0]; af.u[2] = pa[1]; af.u[3] = pb[1];
      // PV: A = P[p=cidx][c=32ks+8q+j], B = V^T from swizzled LDS
      __builtin_amdgcn_s_setprio(1);
#pragma unroll
      for (int nt = 0; nt < 4; nt++) {
        const short8 bfr =
            *(const short8*)&VsB[(nt * 16 + cidx) * 64 + ((ks * 32 + quad * 8) ^ swz)];
        oacc[nt] = mfma16(af.s, bfr, oacc[nt]);
      }
      __builtin_amdgcn_s_setprio(0);
    }
    __syncthreads();  // drains prefetch (vmcnt) + protects buffer reuse
  }

  // reduce srow across quads (lane^16, lane^32 hold same p, disjoint c)
  srow += __shfl_xor(srow, 16, 64);
  srow += __shfl_xor(srow, 32, 64);
  const float sinv = (srow > 0.f) ? 1.0f / srow : 0.f;

#pragma unroll
  for (int r = 0; r < 4; r++) {
    const float sv = __shfl(sinv, quad * 4 + r, 16);  // sinv of p-local quad*4+r
#pragma unroll
    for (int nt = 0; nt < 4; nt++) {
      const size_t off =
          (size_t)(b * PP + p0 + w * 16 + quad * 4 + r) * DD + h * DHH + nt * 16 + cidx;
      ctxb[off] = f2bf(oacc[nt][r] * sv);
    }
  }
}

// ---------------- LayerNorm over D=1024 (bf16 ctx in, f32 out) ----------------
__global__ __launch_bounds__(256) void ln_k(
    const u16* __restrict__ ctxb, float* __restrict__ out,
    const float* __restrict__ gamma, const float* __restrict__ beta) {
  const int row = blockIdx.x, tid = threadIdx.x;
  const int w = tid >> 6, lane = tid & 63;
  const u64 d = *(const u64*)(ctxb + (size_t)row * DD + tid * 4);
  float v0 = bf2f((u16)d);
  float v1 = bf2f((u16)(d >> 16));
  float v2 = bf2f((u16)(d >> 32));
  float v3 = bf2f((u16)(d >> 48));
  float s = v0 + v1 + v2 + v3;
  float sq = v0 * v0 + v1 * v1 + v2 * v2 + v3 * v3;
#pragma unroll
  for (int off = 1; off < 64; off <<= 1) {
    s += __shfl_xor(s, off, 64);
    sq += __shfl_xor(sq, off, 64);
  }
  __shared__ float red[8];
  if (lane == 0) { red[w] = s; red[4 + w] = sq; }
  __syncthreads();
  s = red[0] + red[1] + red[2] + red[3];
  sq = red[4] + red[5] + red[6] + red[7];
  const float mu = s * (1.f / 1024.f);
  const float var = sq * (1.f / 1024.f) - mu * mu;
  const float rs = rsqrtf(fmaxf(var, 0.f) + 1e-6f);
  const float4 gr = *(const float4*)(gamma + tid * 4);
  const float4 br = *(const float4*)(beta + tid * 4);
  float4 y;
  y.x = (v0 - mu) * rs * gr.x + br.x;
  y.y = (v1 - mu) * rs * gr.y + br.y;
  y.z = (v2 - mu) * rs * gr.z + br.z;
  y.w = (v3 - mu) * rs * gr.w + br.w;
  *(float4*)(out + (size_t)row * DD + tid * 4) = y;
}

extern "C" void kernel_launch(void* const* d_in, const int* in_sizes, int n_in,
                              void* d_out, int out_size, void* d_ws, size_t ws_size,
                              hipStream_t stream) {
  const float* para    = (const float*)d_in[0];
  const float* cluster = (const float*)d_in[1];
  const float* edge    = (const float*)d_in[2];
  const float* Wq      = (const float*)d_in[3];
  const float* bq      = (const float*)d_in[4];
  const float* Wk      = (const float*)d_in[5];
  const float* bk      = (const float*)d_in[6];
  const float* Wv      = (const float*)d_in[7];
  const float* bv      = (const float*)d_in[8];
  const float* gamma   = (const float*)d_in[9];
  const float* beta    = (const float*)d_in[10];
  float* out = (float*)d_out;

  // bf16 workspace: 25M u16 = 50 MB
  u16* WqT = (u16*)d_ws;                        // 1M
  u16* WkT = WqT + (size_t)1024 * 1024;         // 1M
  u16* WvT = WkT + (size_t)1024 * 1024;         // 1M
  u16* Qb  = WvT + (size_t)1024 * 1024;         // 8M
  u16* Kp  = Qb  + (size_t)8192 * 1024;         // 2M  [b][h][c][64]
  u16* Vt  = Kp  + (size_t)2048 * 1024;         // 2M  [b][h][d][512]
  u16* Ap  = Vt  + (size_t)2048 * 1024;         // 8M (para bf16; REUSED as bf16 ctx)
  u16* Ac  = Ap  + (size_t)8192 * 1024;         // 2M (cluster bf16)
  u16* Ctx = Ap;   // Ap is dead after qkv_gemm5 -> reuse for bf16 ctx

  prep_k<<<dim3(4096), dim3(256), 0, stream>>>(para, cluster, Wq, Wk, Wv,
                                               Ap, Ac, WqT, WkT, WvT);
  qkv_gemm5<<<dim3(96, 8), dim3(256), 0, stream>>>(Ap, Ac, WqT, WkT, WvT,
                                                   bq, bk, bv, Qb, Kp, Vt);
  attn_k5<<<dim3(PP / 128, HH, BB), dim3(512), 0, stream>>>(Qb, Kp, Vt, edge, Ctx);
  ln_k<<<dim3(BB * PP), dim3(256), 0, stream>>>(Ctx, out, gamma, beta);
}